// Round 4
// baseline (77.778 us; speedup 1.0000x reference)
//
#include <hip/hip_runtime.h>
#include <math.h>

// Problem constants
#define NPIX    65536     // 64*32*32 pixels
#define NELEM   655360    // 64*10*32*32 elements of z
#define NCODE   1024
#define CSTRIDE 1024      // stride between channels in z (h*w)
#define BSTRIDE 10240     // stride between batches in z (c*h*w)
#define NBLK    256       // 1 thread/pixel (R4 mapping — best known)
#define NHB     16        // k_final blocks

// Any code flipping a channel with |v| > SOFT_T has exp(t) == 0 in fp32
// (t < -88 underflows), matching the reference's own fp32 softmax.
// Also guarantees exp(+400a) <= e^88 = 1.65e38 < FLT_MAX (finite inverse factors).
#define SOFT_T 0.22f

// d_ws float offsets. Every word below is unconditionally written each call
// (ticket is zeroed by k_pixel block 0), so NO memset node is needed despite
// 0xAA poisoning.
#define WS_HIST 0                        // [0, 256*1024): per-block hist copies
#define WS_PLP  (NBLK * NCODE)           // +256: per-block plogp sums
#define WS_COM  (WS_PLP + NBLK)          // +256: per-block commit sums
#define WS_ENT  (WS_COM + NBLK)          // +16:  per-k_final-block entropy partials
#define WS_TKT  (WS_ENT + NHB)           // +1:   ticket counter (uint)

// d_out layout (floats):
//   [0, 655360)        z_q_out (sign(z), b,c,h,w like z)
//   [655360..655364]   loss, commit, ent_loss, per_sample_entropy, avg_entropy
//   [655365, 720901)   min_encoding_indices (as float), [b,h,w]

__global__ void __launch_bounds__(256)
k_pixel(const float* __restrict__ z,
        float* __restrict__ zq,
        float* __restrict__ out_idx,
        float* __restrict__ ws) {
    __shared__ float hist[NCODE];
    __shared__ uint4 s_e[256 * 11];   // per-thread soft table: (E bits, invE bits, chan mask, 0)
    __shared__ float2 red[256];

    int tid = threadIdx.x;
    // Zero the node-2 ticket (poison-proof). Visible to k_final at the node
    // boundary — no fence needed.
    if (blockIdx.x == 0 && tid == 0) ((unsigned*)ws)[WS_TKT] = 0u;

    for (int i = tid; i < NCODE; i += 256) hist[i] = 0.f;
    __syncthreads();

    int p = blockIdx.x * 256 + tid;   // pixel id: b*1024 + h*32 + w
    int b = p >> 10;
    int hw = p & 1023;
    const float* zp = z  + b * BSTRIDE + hw;
    float*       qp = zq + b * BSTRIDE + hw;
    uint4* et = &s_e[tid * 11];

    // --- per-pixel: signs, commit, index, PRODUCT-FORM softmax stats ---
    // Z = prod_c (1 + e_c),  sum_n p log p = sum_c t_c*e_c/(1+e_c) - log Z,
    // e_c = exp(-400*|v_c|).  Exact: hard channels give e_c == 0 in fp32.
    int idx = 0, k = 0;
    float commit = 0.f;
    float Z = 1.f, W = 0.f;
#pragma unroll
    for (int c = 0; c < 10; ++c) {
        float x = zp[c * CSTRIDE];
        float h = (x > 0.f) ? 1.f : -1.f;
        qp[c * CSTRIDE] = h;                       // dense, coalesced stores
        float d = h - x;
        commit = fmaf(d, d, commit);
        if (x > 0.f) idx |= (1 << c);
        float a = fabsf(x);
        float t = -400.f * a;
        float e = __expf(t);
        float op = 1.f + e;
        Z *= op;
        W = fmaf(t, e * __builtin_amdgcn_rcpf(op), W);
        if (a < SOFT_T) {
            uint4 u;
            u.x = __float_as_uint(e);              // E  = exp(-400a)  (flip ON factor)
            u.y = __float_as_uint(__expf(-t));     // I  = exp(+400a)  (flip OFF factor, finite)
            u.z = 1u << c;                         // channel mask
            u.w = 0u;
            et[k] = u; ++k;
        }
    }
    out_idx[p] = (float)idx;
    float invZ = __builtin_amdgcn_rcpf(Z);
    float plogp = W - __logf(Z);                   // sum_n p_n log p_n  (<=0)

    // --- pass 2: histogram over soft-channel subsets, Gray order ---
    // Multiplicative weights: w(m) = invZ * prod_{on bits} E_b  — no exp in loop.
    // Bits 0..3 live in registers with COMPILE-TIME flip directions inside each
    // 16-step group (bit3 direction = group parity). Only every 16th step reads
    // LDS (entry b>=4), prefetched one full group (~16 steps) ahead.
    // Entries beyond k are garbage but every use is guarded by (m < nsub).
    uint4 e0 = et[0], e1 = et[1], e2 = et[2], e3 = et[3];
    float E0 = __uint_as_float(e0.x), I0 = __uint_as_float(e0.y);
    float E1 = __uint_as_float(e1.x), I1 = __uint_as_float(e1.y);
    float E2 = __uint_as_float(e2.x), I2 = __uint_as_float(e2.y);
    float E3 = __uint_as_float(e3.x), I3 = __uint_as_float(e3.y);
    unsigned M0 = e0.z, M1 = e1.z, M2 = e2.z, M3 = e3.z;

    int nsub = 1 << k;
    atomicAdd(&hist[idx], invZ);                   // empty subset: p = 1/Z

    float w = invZ;
    unsigned cm = 0, gray = 0;
    uint4 hi = et[4];                              // first hi entry (b=4); guarded
    for (int j = 0, mb = 0; mb + 1 < nsub; mb += 16, ++j) {
        uint4 hin = et[(__ffs(j + 2) - 1) + 4];    // prefetch next group's hi entry
        float f3 = (j & 1) ? I3 : E3;              // bit3 flips once per group
#define STEP(S, FCT, MSK)                                            \
        if (mb + (S) < nsub) {                                       \
            w *= (FCT); cm ^= (MSK);                                 \
            atomicAdd(&hist[idx ^ cm], w);                           \
        }
        // Gray flip sequence for m=1..15 (verified vs g(m)=m^(m>>1)):
        STEP(1,  E0, M0)
        STEP(2,  E1, M1)
        STEP(3,  I0, M0)
        STEP(4,  E2, M2)
        STEP(5,  E0, M0)
        STEP(6,  I1, M1)
        STEP(7,  I0, M0)
        STEP(8,  f3, M3)
        STEP(9,  E0, M0)
        STEP(10, E1, M1)
        STEP(11, I0, M0)
        STEP(12, I2, M2)
        STEP(13, E0, M0)
        STEP(14, I1, M1)
        STEP(15, I0, M0)
#undef STEP
        if (mb + 16 < nsub) {                      // step 16: hi entry b = ctz(j+1)+4
            unsigned bb = 1u << ((__ffs(j + 1) - 1) + 4);
            gray ^= bb;
            float fh = (gray & bb) ? __uint_as_float(hi.x)
                                   : __uint_as_float(hi.y);
            w *= fh; cm ^= hi.z;
            atomicAdd(&hist[idx ^ cm], w);
        }
        hi = hin;
    }

    // --- block-reduce (plogp, commit) ---
    red[tid] = make_float2(plogp, commit);
    __syncthreads();
    for (int st = 128; st > 0; st >>= 1) {
        if (tid < st) {
            red[tid].x += red[tid + st].x;
            red[tid].y += red[tid + st].y;
        }
        __syncthreads();
    }
    if (tid == 0) {
        ws[WS_PLP + blockIdx.x] = red[0].x;
        ws[WS_COM + blockIdx.x] = red[0].y;
    }

    // --- flush private hist copy: float4 coalesced stores, NO atomics ---
    float4* hc = (float4*)(ws + WS_HIST + (size_t)blockIdx.x * NCODE);
    float4* hs = (float4*)hist;
    hc[tid] = hs[tid];                             // 256 threads x 16B = 4KB
}

// Node 2: 16 blocks x 1024 threads. Block b reduces bins [b*64, b*64+64) over
// the 256 copies and writes its entropy partial; the LAST block to finish
// (device-scope ticket) additionally runs the exact former k_scalars body.
// Arithmetic order is identical to the proven 3-kernel version -> bit-exact.
__global__ void __launch_bounds__(1024)
k_final(const float* __restrict__ ws_r, float* __restrict__ ws,
        float* __restrict__ out_sc) {
    __shared__ float sh[16 * 64];
    __shared__ float2 red[256];
    __shared__ int s_tkt;

    int t = threadIdx.x;
    int lane = t & 63;
    int w = t >> 6;                                // 16 copy-groups
    int bin = blockIdx.x * 64 + lane;
    float acc = 0.f;
#pragma unroll 4
    for (int c = w; c < NBLK; c += 16)
        acc += ws_r[WS_HIST + (size_t)c * NCODE + bin];   // 256B coalesced per wave
    sh[w * 64 + lane] = acc;
    __syncthreads();
    if (t < 64) {
        float a = sh[lane];
#pragma unroll
        for (int g = 1; g < 16; ++g) a += sh[g * 64 + lane];
        a *= (1.f / 65536.f);                      // avg_probs[bin]
        float ent = -a * __logf(a + 1e-5f);
#pragma unroll
        for (int off = 32; off > 0; off >>= 1)
            ent += __shfl_down(ent, off, 64);
        if (lane == 0) ws[WS_ENT + blockIdx.x] = ent;
    }

    // --- release my partial, draw a ticket (device scope; only 16 fences) ---
    __threadfence();
    __syncthreads();
    if (t == 0)
        s_tkt = (int)atomicAdd((unsigned*)ws + WS_TKT, 1u);
    __syncthreads();
    if (s_tkt != NHB - 1) return;                  // not last -> done

    // --- last block: all 16 WS_ENT partials are fenced-out; acquire & finish ---
    __threadfence();

    if (t < 256) red[t] = make_float2(ws_r[WS_PLP + t], ws_r[WS_COM + t]);
    __syncthreads();
    for (int st = 128; st > 0; st >>= 1) {
        if (t < st) {
            red[t].x += red[t + st].x;
            red[t].y += red[t + st].y;
        }
        __syncthreads();
    }
    if (t == 0) {
        float avg_entropy = 0.f;
#pragma unroll
        for (int g = 0; g < NHB; ++g) avg_entropy += ws[WS_ENT + g];
        float pse = -red[0].x * (1.f / 65536.f);   // per_sample_entropy
        float cl  = 0.25f * red[0].y * (1.f / (float)NELEM);
        float el  = 0.1f * (pse - avg_entropy);
        out_sc[0] = cl + el;                       // loss
        out_sc[1] = cl;
        out_sc[2] = el;
        out_sc[3] = pse;
        out_sc[4] = avg_entropy;
    }
}

extern "C" void kernel_launch(void* const* d_in, const int* in_sizes, int n_in,
                              void* d_out, int out_size, void* d_ws, size_t ws_size,
                              hipStream_t stream) {
    const float* z = (const float*)d_in[0];
    float* out = (float*)d_out;
    float* ws = (float*)d_ws;

    k_pixel<<<NBLK, 256, 0, stream>>>(z, out, out + NELEM + 5, ws);
    k_final<<<NHB, 1024, 0, stream>>>(ws, ws, out + NELEM);
}

// Round 5
// 71.678 us; speedup vs baseline: 1.0851x; 1.0851x over previous
//
#include <hip/hip_runtime.h>
#include <math.h>

// Problem constants
#define NPIX    65536     // 64*32*32 pixels
#define NELEM   655360    // 64*10*32*32 elements of z
#define NCODE   1024
#define CSTRIDE 1024      // stride between channels in z (h*w)
#define BSTRIDE 10240     // stride between batches in z (c*h*w)
#define NBLK    256       // 1 thread/pixel (R4 mapping — best known)
#define NHB     16        // k_final blocks

// Any code flipping a channel with |v| > SOFT_T has exp(t) == 0 in fp32
// (t < -88 underflows), matching the reference's own fp32 softmax.
// Also guarantees exp(+400a) <= e^88 = 1.65e38 < FLT_MAX (finite inverse factors).
#define SOFT_T 0.22f

// d_ws float offsets. Every word below is unconditionally written each call
// (ticket is zeroed by k_pixel block 0), so NO memset node is needed despite
// 0xAA poisoning.
#define WS_HIST 0                        // [0, 256*1024): per-block hist copies
#define WS_PLP  (NBLK * NCODE)           // +256: per-block plogp sums
#define WS_COM  (WS_PLP + NBLK)          // +256: per-block commit sums
#define WS_ENT  (WS_COM + NBLK)          // +16:  per-k_final-block entropy partials
#define WS_TKT  (WS_ENT + NHB)           // +1:   ticket counter (uint)

// d_out layout (floats):
//   [0, 655360)        z_q_out (sign(z), b,c,h,w like z)
//   [655360..655364]   loss, commit, ent_loss, per_sample_entropy, avg_entropy
//   [655365, 720901)   min_encoding_indices (as float), [b,h,w]

__global__ void __launch_bounds__(256)
k_pixel(const float* __restrict__ z,
        float* __restrict__ zq,
        float* __restrict__ out_idx,
        float* __restrict__ ws) {
    __shared__ float hist[NCODE];
    __shared__ uint4 s_e[256 * 11];   // per-thread soft table: (E bits, invE bits, chan mask, 0)
    __shared__ float2 red[256];

    int tid = threadIdx.x;
    // Zero the node-2 ticket (poison-proof). Visible to k_final at the node
    // boundary — no fence needed.
    if (blockIdx.x == 0 && tid == 0) ((unsigned*)ws)[WS_TKT] = 0u;

    for (int i = tid; i < NCODE; i += 256) hist[i] = 0.f;
    __syncthreads();

    int p = blockIdx.x * 256 + tid;   // pixel id: b*1024 + h*32 + w
    int b = p >> 10;
    int hw = p & 1023;
    const float* zp = z  + b * BSTRIDE + hw;
    float*       qp = zq + b * BSTRIDE + hw;
    uint4* et = &s_e[tid * 11];

    // --- per-pixel: signs, commit, index, PRODUCT-FORM softmax stats ---
    // Z = prod_c (1 + e_c),  sum_n p log p = sum_c t_c*e_c/(1+e_c) - log Z,
    // e_c = exp(-400*|v_c|).  Exact: hard channels give e_c == 0 in fp32.
    int idx = 0, k = 0;
    float commit = 0.f;
    float Z = 1.f, W = 0.f;
#pragma unroll
    for (int c = 0; c < 10; ++c) {
        float x = zp[c * CSTRIDE];
        float h = (x > 0.f) ? 1.f : -1.f;
        qp[c * CSTRIDE] = h;                       // dense, coalesced stores
        float d = h - x;
        commit = fmaf(d, d, commit);
        if (x > 0.f) idx |= (1 << c);
        float a = fabsf(x);
        float t = -400.f * a;
        float e = __expf(t);
        float op = 1.f + e;
        Z *= op;
        W = fmaf(t, e * __builtin_amdgcn_rcpf(op), W);
        if (a < SOFT_T) {
            uint4 u;
            u.x = __float_as_uint(e);              // E  = exp(-400a)  (flip ON factor)
            u.y = __float_as_uint(__expf(-t));     // I  = exp(+400a)  (flip OFF factor, finite)
            u.z = 1u << c;                         // channel mask
            u.w = 0u;
            et[k] = u; ++k;
        }
    }
    out_idx[p] = (float)idx;
    float invZ = __builtin_amdgcn_rcpf(Z);
    float plogp = W - __logf(Z);                   // sum_n p_n log p_n  (<=0)

    // --- pass 2: histogram over soft-channel subsets, Gray order ---
    // Multiplicative weights: w(m) = invZ * prod_{on bits} E_b  — no exp in loop.
    // Bits 0..3 live in registers with COMPILE-TIME flip directions inside each
    // 16-step group (bit3 direction = group parity). Only every 16th step reads
    // LDS (entry b>=4), prefetched one full group (~16 steps) ahead.
    // Entries beyond k are garbage but every use is guarded by (m < nsub).
    uint4 e0 = et[0], e1 = et[1], e2 = et[2], e3 = et[3];
    float E0 = __uint_as_float(e0.x), I0 = __uint_as_float(e0.y);
    float E1 = __uint_as_float(e1.x), I1 = __uint_as_float(e1.y);
    float E2 = __uint_as_float(e2.x), I2 = __uint_as_float(e2.y);
    float E3 = __uint_as_float(e3.x), I3 = __uint_as_float(e3.y);
    unsigned M0 = e0.z, M1 = e1.z, M2 = e2.z, M3 = e3.z;

    int nsub = 1 << k;
    atomicAdd(&hist[idx], invZ);                   // empty subset: p = 1/Z

    float w = invZ;
    unsigned cm = 0, gray = 0;
    uint4 hi = et[4];                              // first hi entry (b=4); guarded
    for (int j = 0, mb = 0; mb + 1 < nsub; mb += 16, ++j) {
        uint4 hin = et[(__ffs(j + 2) - 1) + 4];    // prefetch next group's hi entry
        float f3 = (j & 1) ? I3 : E3;              // bit3 flips once per group
#define STEP(S, FCT, MSK)                                            \
        if (mb + (S) < nsub) {                                       \
            w *= (FCT); cm ^= (MSK);                                 \
            atomicAdd(&hist[idx ^ cm], w);                           \
        }
        // Gray flip sequence for m=1..15 (verified vs g(m)=m^(m>>1)):
        STEP(1,  E0, M0)
        STEP(2,  E1, M1)
        STEP(3,  I0, M0)
        STEP(4,  E2, M2)
        STEP(5,  E0, M0)
        STEP(6,  I1, M1)
        STEP(7,  I0, M0)
        STEP(8,  f3, M3)
        STEP(9,  E0, M0)
        STEP(10, E1, M1)
        STEP(11, I0, M0)
        STEP(12, I2, M2)
        STEP(13, E0, M0)
        STEP(14, I1, M1)
        STEP(15, I0, M0)
#undef STEP
        if (mb + 16 < nsub) {                      // step 16: hi entry b = ctz(j+1)+4
            unsigned bb = 1u << ((__ffs(j + 1) - 1) + 4);
            gray ^= bb;
            float fh = (gray & bb) ? __uint_as_float(hi.x)
                                   : __uint_as_float(hi.y);
            w *= fh; cm ^= hi.z;
            atomicAdd(&hist[idx ^ cm], w);
        }
        hi = hin;
    }

    // --- block-reduce (plogp, commit) ---
    red[tid] = make_float2(plogp, commit);
    __syncthreads();
    for (int st = 128; st > 0; st >>= 1) {
        if (tid < st) {
            red[tid].x += red[tid + st].x;
            red[tid].y += red[tid + st].y;
        }
        __syncthreads();
    }
    if (tid == 0) {
        ws[WS_PLP + blockIdx.x] = red[0].x;
        ws[WS_COM + blockIdx.x] = red[0].y;
    }

    // --- flush private hist copy: float4 coalesced stores, NO atomics ---
    float4* hc = (float4*)(ws + WS_HIST + (size_t)blockIdx.x * NCODE);
    float4* hs = (float4*)hist;
    hc[tid] = hs[tid];                             // 256 threads x 16B = 4KB
}

// Node 2: 16 blocks x 1024 threads. Block b reduces bins [b*64, b*64+64) over
// the 256 copies and writes its entropy partial; the LAST block (device-scope
// ticket) additionally runs the exact former k_scalars body.
//
// LEAN SYNC (R4 regression was a 272-wave __threadfence storm): the only
// cross-block value is ws[WS_ENT+blk], stored by thread 0 — the SAME thread
// that draws the ticket. One ACQ_REL agent-scope RMW per block both releases
// that store and (for the block reading 15) acquires the whole release
// sequence. 16 device-scope ops total; zero __threadfence.
// WS_PLP/WS_COM/WS_HIST come from the previous kernel node (implicit dispatch
// acquire) — no fence needed. Arithmetic order identical to the proven
// 3-kernel version -> bit-exact.
__global__ void __launch_bounds__(1024)
k_final(const float* __restrict__ ws_r, float* __restrict__ ws,
        float* __restrict__ out_sc) {
    __shared__ float sh[16 * 64];
    __shared__ float2 red[256];
    __shared__ int s_tkt;

    int t = threadIdx.x;
    int lane = t & 63;
    int w = t >> 6;                                // 16 copy-groups
    int bin = blockIdx.x * 64 + lane;
    float acc = 0.f;
#pragma unroll 4
    for (int c = w; c < NBLK; c += 16)
        acc += ws_r[WS_HIST + (size_t)c * NCODE + bin];   // 256B coalesced per wave
    sh[w * 64 + lane] = acc;
    __syncthreads();
    if (t < 64) {
        float a = sh[lane];
#pragma unroll
        for (int g = 1; g < 16; ++g) a += sh[g * 64 + lane];
        a *= (1.f / 65536.f);                      // avg_probs[bin]
        float ent = -a * __logf(a + 1e-5f);
#pragma unroll
        for (int off = 32; off > 0; off >>= 1)
            ent += __shfl_down(ent, off, 64);
        if (lane == 0) {
            ws[WS_ENT + blockIdx.x] = ent;         // plain store (t == 0)
            // Release my partial + draw ticket in ONE agent-scope RMW.
            s_tkt = (int)__hip_atomic_fetch_add((unsigned*)ws + WS_TKT, 1u,
                                                __ATOMIC_ACQ_REL,
                                                __HIP_MEMORY_SCOPE_AGENT);
        }
    }
    __syncthreads();
    if (s_tkt != NHB - 1) return;                  // not last -> done

    // --- last block: ticket RMW (read 15) acquired all 16 WS_ENT stores;
    //     the only WS_ENT reader is thread 0, the acquiring thread. ---
    if (t < 256) red[t] = make_float2(ws_r[WS_PLP + t], ws_r[WS_COM + t]);
    __syncthreads();
    for (int st = 128; st > 0; st >>= 1) {
        if (t < st) {
            red[t].x += red[t + st].x;
            red[t].y += red[t + st].y;
        }
        __syncthreads();
    }
    if (t == 0) {
        float avg_entropy = 0.f;
#pragma unroll
        for (int g = 0; g < NHB; ++g) avg_entropy += ws[WS_ENT + g];
        float pse = -red[0].x * (1.f / 65536.f);   // per_sample_entropy
        float cl  = 0.25f * red[0].y * (1.f / (float)NELEM);
        float el  = 0.1f * (pse - avg_entropy);
        out_sc[0] = cl + el;                       // loss
        out_sc[1] = cl;
        out_sc[2] = el;
        out_sc[3] = pse;
        out_sc[4] = avg_entropy;
    }
}

extern "C" void kernel_launch(void* const* d_in, const int* in_sizes, int n_in,
                              void* d_out, int out_size, void* d_ws, size_t ws_size,
                              hipStream_t stream) {
    const float* z = (const float*)d_in[0];
    float* out = (float*)d_out;
    float* ws = (float*)d_ws;

    k_pixel<<<NBLK, 256, 0, stream>>>(z, out, out + NELEM + 5, ws);
    k_final<<<NHB, 1024, 0, stream>>>(ws, ws, out + NELEM);
}

// Round 6
// 71.180 us; speedup vs baseline: 1.0927x; 1.0070x over previous
//
#include <hip/hip_runtime.h>
#include <math.h>

// Problem constants
#define NPIX    65536     // 64*32*32 pixels
#define NELEM   655360    // 64*10*32*32 elements of z
#define NCODE   1024
#define CSTRIDE 1024      // stride between channels in z (h*w)
#define BSTRIDE 10240     // stride between batches in z (c*h*w)
#define NBLK    512       // k_pixel blocks: 128 pixels/block, 2 threads/pixel
#define NHB     16        // k_final blocks

// Any code flipping a channel with |v| > SOFT_T has exp(t) == 0 in fp32
// (t < -88 underflows), matching the reference's own fp32 softmax.
// Also guarantees exp(+400a) <= e^88 = 1.65e38 < FLT_MAX (finite inverse factors).
#define SOFT_T 0.22f

// d_ws float offsets. Every word below is unconditionally written each call
// (ticket is zeroed by k_pixel block 0), so NO memset node is needed despite
// 0xAA poisoning.
#define WS_HIST 0                        // [0, 512*1024): per-block hist copies
#define WS_PLP  (NBLK * NCODE)           // +512: per-block plogp sums
#define WS_COM  (WS_PLP + NBLK)          // +512: per-block commit sums
#define WS_ENT  (WS_COM + NBLK)          // +16:  per-k_final-block entropy partials
#define WS_TKT  (WS_ENT + NHB)           // +1:   ticket counter (uint)

// d_out layout (floats):
//   [0, 655360)        z_q_out (sign(z), b,c,h,w like z)
//   [655360..655364]   loss, commit, ent_loss, per_sample_entropy, avg_entropy
//   [655365, 720901)   min_encoding_indices (as float), [b,h,w]

// 2 threads per pixel: tid&127 selects the pixel, r = tid>>7 selects which
// half of the subset lattice this thread enumerates (bit k-1 == r). This
// halves the serial straggler depth AND doubles occupancy (512 blocks =
// 2 blocks/CU = 8 waves/CU) — k_pixel at 1 wave/SIMD was pure exposed latency.
__global__ void __launch_bounds__(256)
k_pixel(const float* __restrict__ z,
        float* __restrict__ zq,
        float* __restrict__ out_idx,
        float* __restrict__ ws) {
    __shared__ float hist[NCODE];
    __shared__ uint4 s_e[256 * 11];   // per-thread soft table: (E bits, invE bits, chan mask, 0)
    __shared__ float2 red[256];

    int tid = threadIdx.x;
    // Zero the node-2 ticket (poison-proof). Visible to k_final at the node
    // boundary — no fence needed.
    if (blockIdx.x == 0 && tid == 0) ((unsigned*)ws)[WS_TKT] = 0u;

    for (int i = tid; i < NCODE; i += 256) hist[i] = 0.f;
    __syncthreads();

    int r = tid >> 7;                 // subset-half role (0: bit k-1 clear, 1: set)
    int pid = blockIdx.x * 128 + (tid & 127);   // pixel id: b*1024 + h*32 + w
    int b = pid >> 10;
    int hw = pid & 1023;
    const float* zp = z  + b * BSTRIDE + hw;
    float*       qp = zq + b * BSTRIDE + hw;
    uint4* et = &s_e[tid * 11];

    // --- per-pixel: signs, commit, index, PRODUCT-FORM softmax stats ---
    // Z = prod_c (1 + e_c),  sum_n p log p = sum_c t_c*e_c/(1+e_c) - log Z,
    // e_c = exp(-400*|v_c|).  Exact: hard channels give e_c == 0 in fp32.
    // Duplicated across the pixel's 2 threads (z re-read hits L1/L2); only
    // r==0 stores zq/out_idx and contributes to the scalar reductions.
    int idx = 0, k = 0;
    float commit = 0.f;
    float Z = 1.f, W = 0.f;
    float lastE = 0.f; unsigned lastM = 0u;        // entry k-1 (for r==1 base)
#pragma unroll
    for (int c = 0; c < 10; ++c) {
        float x = zp[c * CSTRIDE];
        float h = (x > 0.f) ? 1.f : -1.f;
        if (r == 0) qp[c * CSTRIDE] = h;           // dense, coalesced stores
        float d = h - x;
        commit = fmaf(d, d, commit);
        if (x > 0.f) idx |= (1 << c);
        float a = fabsf(x);
        float t = -400.f * a;
        float e = __expf(t);
        float op = 1.f + e;
        Z *= op;
        W = fmaf(t, e * __builtin_amdgcn_rcpf(op), W);
        if (a < SOFT_T) {
            uint4 u;
            u.x = __float_as_uint(e);              // E  = exp(-400a)  (flip ON factor)
            u.y = __float_as_uint(__expf(-t));     // I  = exp(+400a)  (flip OFF factor, finite)
            u.z = 1u << c;                         // channel mask
            u.w = 0u;
            et[k] = u; ++k;
            lastE = e; lastM = u.z;
        }
    }
    if (r == 0) out_idx[pid] = (float)idx;
    float invZ = __builtin_amdgcn_rcpf(Z);
    float plogp = W - __logf(Z);                   // sum_n p_n log p_n  (<=0)

    // --- pass 2: histogram over HALF the soft-subset lattice, Gray order ---
    // This thread owns subsets with bit (k-1) == r; enumerate bits 0..k-2.
    // Multiplicative weights (no exp in loop); bits 0..3 in registers with
    // compile-time flip directions per 16-step group; LDS read only every
    // 16th step, prefetched a group ahead. Guarded reads of garbage entries ok.
    uint4 e0 = et[0], e1 = et[1], e2 = et[2], e3 = et[3];
    float E0 = __uint_as_float(e0.x), I0 = __uint_as_float(e0.y);
    float E1 = __uint_as_float(e1.x), I1 = __uint_as_float(e1.y);
    float E2 = __uint_as_float(e2.x), I2 = __uint_as_float(e2.y);
    float E3 = __uint_as_float(e3.x), I3 = __uint_as_float(e3.y);
    unsigned M0 = e0.z, M1 = e1.z, M2 = e2.z, M3 = e3.z;

    int kk = (k > 0) ? (k - 1) : 0;                // enumerated bit count
    int nsub = 1 << kk;
    bool active = (r == 0) || (k > 0);             // r==1,k==0: nothing to do

    float w = invZ;
    int hidx = idx;
    if (r == 1) { w *= lastE; hidx ^= lastM; }     // base: bit k-1 set
    if (active) atomicAdd(&hist[hidx], w);         // base subset

    unsigned cm = 0, gray = 0;
    uint4 hi = et[4];                              // first hi entry (bit 4); guarded
    for (int j = 0, mb = 0; mb + 1 < nsub; mb += 16, ++j) {
        uint4 hin = et[(__ffs(j + 2) - 1) + 4];    // prefetch next group's hi entry
        float f3 = (j & 1) ? I3 : E3;              // bit3 flips once per group
#define STEP(S, FCT, MSK)                                            \
        if (mb + (S) < nsub) {                                       \
            w *= (FCT); cm ^= (MSK);                                 \
            atomicAdd(&hist[hidx ^ cm], w);                          \
        }
        // Gray flip sequence for m=1..15 (verified vs g(m)=m^(m>>1)):
        STEP(1,  E0, M0)
        STEP(2,  E1, M1)
        STEP(3,  I0, M0)
        STEP(4,  E2, M2)
        STEP(5,  E0, M0)
        STEP(6,  I1, M1)
        STEP(7,  I0, M0)
        STEP(8,  f3, M3)
        STEP(9,  E0, M0)
        STEP(10, E1, M1)
        STEP(11, I0, M0)
        STEP(12, I2, M2)
        STEP(13, E0, M0)
        STEP(14, I1, M1)
        STEP(15, I0, M0)
#undef STEP
        if (mb + 16 < nsub) {                      // step 16: hi entry bit = ctz(j+1)+4
            unsigned bb = 1u << ((__ffs(j + 1) - 1) + 4);
            gray ^= bb;
            float fh = (gray & bb) ? __uint_as_float(hi.x)
                                   : __uint_as_float(hi.y);
            w *= fh; cm ^= hi.z;
            atomicAdd(&hist[hidx ^ cm], w);
        }
        hi = hin;
    }

    // --- block-reduce (plogp, commit): r==1 contributes zeros ---
    red[tid] = (r == 0) ? make_float2(plogp, commit) : make_float2(0.f, 0.f);
    __syncthreads();
    for (int st = 128; st > 0; st >>= 1) {
        if (tid < st) {
            red[tid].x += red[tid + st].x;
            red[tid].y += red[tid + st].y;
        }
        __syncthreads();
    }
    if (tid == 0) {
        ws[WS_PLP + blockIdx.x] = red[0].x;
        ws[WS_COM + blockIdx.x] = red[0].y;
    }

    // --- flush private hist copy: float4 coalesced stores, NO atomics ---
    float4* hc = (float4*)(ws + WS_HIST + (size_t)blockIdx.x * NCODE);
    float4* hs = (float4*)hist;
    hc[tid] = hs[tid];                             // 256 threads x 16B = 4KB
}

// Node 2: 16 blocks x 1024 threads. Block b reduces bins [b*64, b*64+64) over
// the 512 copies and writes its entropy partial; the LAST block (device-scope
// ticket) additionally runs the scalar epilogue.
// LEAN SYNC (R4 lesson: per-wave __threadfence storms cost ~6 µs): the only
// cross-block value is ws[WS_ENT+blk], stored by thread 0 — the SAME thread
// that draws the ticket. One ACQ_REL agent-scope RMW per block both releases
// that store and (for the block reading 15) acquires the release sequence.
__global__ void __launch_bounds__(1024)
k_final(const float* __restrict__ ws_r, float* __restrict__ ws,
        float* __restrict__ out_sc) {
    __shared__ float sh[16 * 64];
    __shared__ float2 red[256];
    __shared__ int s_tkt;

    int t = threadIdx.x;
    int lane = t & 63;
    int w = t >> 6;                                // 16 copy-groups
    int bin = blockIdx.x * 64 + lane;
    float acc = 0.f;
#pragma unroll 4
    for (int c = w; c < NBLK; c += 16)
        acc += ws_r[WS_HIST + (size_t)c * NCODE + bin];   // 256B coalesced per wave
    sh[w * 64 + lane] = acc;
    __syncthreads();
    if (t < 64) {
        float a = sh[lane];
#pragma unroll
        for (int g = 1; g < 16; ++g) a += sh[g * 64 + lane];
        a *= (1.f / 65536.f);                      // avg_probs[bin]
        float ent = -a * __logf(a + 1e-5f);
#pragma unroll
        for (int off = 32; off > 0; off >>= 1)
            ent += __shfl_down(ent, off, 64);
        if (lane == 0) {
            ws[WS_ENT + blockIdx.x] = ent;         // plain store (t == 0)
            // Release my partial + draw ticket in ONE agent-scope RMW.
            s_tkt = (int)__hip_atomic_fetch_add((unsigned*)ws + WS_TKT, 1u,
                                                __ATOMIC_ACQ_REL,
                                                __HIP_MEMORY_SCOPE_AGENT);
        }
    }
    __syncthreads();
    if (s_tkt != NHB - 1) return;                  // not last -> done

    // --- last block: ticket RMW (read 15) acquired all 16 WS_ENT stores;
    //     the only WS_ENT reader is thread 0, the acquiring thread. ---
    if (t < 256)
        red[t] = make_float2(ws_r[WS_PLP + t] + ws_r[WS_PLP + 256 + t],
                             ws_r[WS_COM + t] + ws_r[WS_COM + 256 + t]);
    __syncthreads();
    for (int st = 128; st > 0; st >>= 1) {
        if (t < st) {
            red[t].x += red[t + st].x;
            red[t].y += red[t + st].y;
        }
        __syncthreads();
    }
    if (t == 0) {
        float avg_entropy = 0.f;
#pragma unroll
        for (int g = 0; g < NHB; ++g) avg_entropy += ws[WS_ENT + g];
        float pse = -red[0].x * (1.f / 65536.f);   // per_sample_entropy
        float cl  = 0.25f * red[0].y * (1.f / (float)NELEM);
        float el  = 0.1f * (pse - avg_entropy);
        out_sc[0] = cl + el;                       // loss
        out_sc[1] = cl;
        out_sc[2] = el;
        out_sc[3] = pse;
        out_sc[4] = avg_entropy;
    }
}

extern "C" void kernel_launch(void* const* d_in, const int* in_sizes, int n_in,
                              void* d_out, int out_size, void* d_ws, size_t ws_size,
                              hipStream_t stream) {
    const float* z = (const float*)d_in[0];
    float* out = (float*)d_out;
    float* ws = (float*)d_ws;

    k_pixel<<<NBLK, 256, 0, stream>>>(z, out, out + NELEM + 5, ws);
    k_final<<<NHB, 1024, 0, stream>>>(ws, ws, out + NELEM);
}